// Round 7
// baseline (234.828 us; speedup 1.0000x reference)
//
#include <hip/hip_runtime.h>
#include <math.h>

// EquiGroupSamplingIco — round 17: k_fsig VALU diet + TLP.
// R16 counters: k_fsig 62.6us, VALUBusy 42%, MfmaUtil 27%, occupancy 19%
// (2 blocks/CU), ~2300 cyc/block-iter vs ~200 cyc MFMA. Dominators: (a) 32
// hand-rolled f2bf per thread/iter (~220 VALU ops, serially dependent on sig
// MFMAs); (b) grid pinned at 512 -> no TLP to hide dinf L2 latency + barrier
// drains.
// Fix (k_fsig only):
//  - v_cvt_pk_bf16_f32 inline asm: 32 converts -> 16 one-op packed.
//  - sig phase: 8 independent MFMAs issued first, then max+cvt_pk, then 8B
//    uint2 stores (same swizzle).
//  - dinf prefetched one iter ahead in registers.
//  - 4-way split-K: grid 1024 (4 blocks/CU, 16 iters). part = 4 splits
//    (33.5MB) aliased into sigb's SECOND half (trajbf uses first half only;
//    part consumed by k_red before k_batchX runs). DinB moved after part and
//    null-gated in k_pre for the small-ws fallback.
//  - k_red sums 4 bf16 splits.
// Everything else unchanged from R16.

#define NBT  512
#define F8c  16
#define F2c  64
#define GJ   455
#define GG   4096
#define NICO 60
#define JP   512      // padded j for trajbf / icoB

typedef short bf16x8 __attribute__((ext_vector_type(8)));
typedef float f32x4  __attribute__((ext_vector_type(4)));
typedef unsigned short u16x4 __attribute__((ext_vector_type(4)));
typedef unsigned int u32;
typedef unsigned short ushort;

struct W7 { const float* p[7]; };

__device__ __forceinline__ ushort f2bf(float f) {
  u32 u = __float_as_uint(f);
  return (ushort)((u + 0x7fffu + ((u >> 16) & 1u)) >> 16);   // RNE
}
__device__ __forceinline__ float bf2f(ushort v) {
  return __uint_as_float(((u32)v) << 16);
}
__device__ __forceinline__ u32 cvtpk(float lo, float hi) {   // 2xf32 -> 2xbf16 (RNE)
  u32 r;
  asm("v_cvt_pk_bf16_f32 %0, %1, %2" : "=v"(r) : "v"(lo), "v"(hi));
  return r;
}

__device__ __forceinline__ int sel7(int l, int a0, int a1, int a2, int a3,
                                    int a4, int a5, int a6) {
  int r = a6;
  r = (l == 5) ? a5 : r; r = (l == 4) ? a4 : r; r = (l == 3) ? a3 : r;
  r = (l == 2) ? a2 : r; r = (l == 1) ? a1 : r; r = (l == 0) ? a0 : r;
  return r;
}
__device__ __forceinline__ float sel7f(int l, float a0, float a1, float a2,
                                       float a3, float a4, float a5, float a6) {
  float r = a6;
  r = (l == 5) ? a5 : r; r = (l == 4) ? a4 : r; r = (l == 3) ? a3 : r;
  r = (l == 2) ? a2 : r; r = (l == 1) ? a1 : r; r = (l == 0) ? a0 : r;
  return r;
}

// ---------------- k_pre: fused preprocessing (DinB null-gated) ----------------
__global__ __launch_bounds__(256) void k_pre(const float* __restrict__ traj,
                                             const float* __restrict__ w1s,
                                             const float* __restrict__ w1v,
                                             const float* __restrict__ ico,
                                             const float* __restrict__ Dout,
                                             const float* __restrict__ Din,
                                             W7 w2,
                                             float* __restrict__ h,
                                             ushort* __restrict__ icoB,
                                             ushort* __restrict__ icoBx,
                                             ushort* __restrict__ DoutBT,
                                             ushort* __restrict__ Abuf,
                                             ushort* __restrict__ Bbuf,
                                             ushort* __restrict__ DinB) {
  __shared__ float t[64][65];
  int b = blockIdx.x, tid = threadIdx.x;
  if (b < 2240) {
    ((uint4*)Abuf)[b * 256 + tid] = (uint4){0, 0, 0, 0};
  } else if (b < 2752) {
    int b2 = b - 2240;
    int jt = b2 & 7, kt = b2 >> 3;
    int tx = tid & 63, ty = tid >> 6;
    #pragma unroll
    for (int i = 0; i < 16; ++i) {
      int r = i * 4 + ty, j = jt * 64 + tx;
      t[r][tx] = (j < GJ) ? Dout[(size_t)(kt * 64 + r) * GJ + j] : 0.f;
    }
    __syncthreads();
    #pragma unroll
    for (int i = 0; i < 16; ++i) {
      int jl = i * 4 + ty;
      DoutBT[(size_t)(jt * 64 + jl) * GG + kt * 64 + tx] = f2bf(t[tx][jl]);
    }
  } else if (b < 4992) {
    int ee = (b - 2752) * 256 + tid;
    if (ee < 573440) {
      int l = (ee >= 4096) + (ee >= 16384) + (ee >= 57344) + (ee >= 114688) +
              (ee >= 225280) + (ee >= 360448);
      int base = sel7(l, 0, 4096, 16384, 57344, 114688, 225280, 360448);
      int d    = sel7(l, 1, 3, 5, 7, 9, 11, 13);
      int Kp   = sel7(l, 64, 64, 128, 128, 192, 192, 256);
      int local = ee - base;
      int row = local / Kp, kcol = local - row * Kp;
      int g2 = row / d, v = row - g2 * d;
      ushort val = 0;
      if (kcol < 16 * d) {
        int f = kcol / d, u = kcol - f * d;
        const float* wl = w2.p[l];
        float scl = rsqrtf(16.f * (float)d);
        val = f2bf(wl[(((size_t)f * 64 + g2) * d + u) * d + v] * scl);
      }
      Bbuf[ee] = val;
    }
  } else if (b < 5312) {
    int idx = (b - 4992) * 256 + tid;
    if (idx < NBT * 160) {
      int bt = idx / 160, r = idx % 160, c = r / 10, i = r % 10;
      const float* tr = traj + bt * 10;
      float val;
      if (i == 0) {
        val = tr[9] * w1s[c];
      } else {
        int k = i - 1, v = k / 3, m = k % 3;
        float s = 0.f;
        #pragma unroll
        for (int u = 0; u < 3; ++u) s = fmaf(tr[u * 3 + m], w1v[c * 9 + u * 3 + v], s);
        val = s * 0.57735026918962576f;
      }
      h[idx] = val;
    }
  } else if (b < 5440) {
    // icoB, kappa-permuted: icoB[i][o + m*d + v] = ico[i][o + v*d + m]
    int e = (b - 5312) * 256 + tid;   // 32768
    int i = e >> 9, k = e & 511;
    ushort val = 0;
    if (i < NICO && k < GJ) {
      int l = (k >= 1) + (k >= 10) + (k >= 35) + (k >= 84) + (k >= 165) + (k >= 286);
      int o = sel7(l, 0, 1, 10, 35, 84, 165, 286);
      int d = sel7(l, 1, 3, 5, 7, 9, 11, 13);
      float rcpd = sel7f(l, 1.f, 1.f / 3.f, 0.2f, 1.f / 7.f, 1.f / 9.f,
                         1.f / 11.f, 1.f / 13.f);
      int local = k - o;
      int m = (int)(((float)local + 0.5f) * rcpd);   // exact (margin >> eps)
      int v = local - m * d;
      val = f2bf(ico[i * GJ + o + v * d + m]);
    }
    icoB[e] = val;
  } else if (b < 5568) {
    // icoBx, original j-order (for the xg GEMM: x is in j-order)
    int e = (b - 5440) * 256 + tid;   // 32768
    int i = e >> 9, j = e & 511;
    icoBx[e] = (i < NICO && j < GJ) ? f2bf(ico[i * GJ + j]) : (ushort)0;
  } else {
    // DinB: [4096 g][32 k] bf16, k<10 from Din, rest 0. Main path only.
    if (DinB != nullptr) {
      int g = (b - 5568) * 256 + tid;   // 4096
      const float* dr = Din + (size_t)g * 10;
      #pragma unroll
      for (int k = 0; k < 32; ++k)
        DinB[(size_t)g * 32 + k] = (k < 10) ? f2bf(dr[k]) : (ushort)0;
    }
  }
}

// ---------------- k_sig (fallback path only, unchanged) ----------------
__global__ __launch_bounds__(256) void k_sig(const float* __restrict__ h,
                                             const float* __restrict__ Din,
                                             ushort* __restrict__ sigb) {
  __shared__ float hs[160];
  int tid = threadIdx.x;
  int mb = blockIdx.y;
  int kt = blockIdx.x;           // 0..1
  if (tid < 160) hs[tid] = h[mb * 160 + tid];
  float dr[80];
  const float4* dp = (const float4*)(Din + (size_t)(kt * 2048 + tid * 8) * 10);
  #pragma unroll
  for (int q = 0; q < 20; ++q) {
    float4 v = dp[q];
    dr[q * 4 + 0] = v.x; dr[q * 4 + 1] = v.y; dr[q * 4 + 2] = v.z; dr[q * 4 + 3] = v.w;
  }
  __syncthreads();
  #pragma unroll
  for (int r = 0; r < 16; ++r) {
    float hv[10];
    #pragma unroll
    for (int i = 0; i < 10; ++i) hv[i] = hs[r * 10 + i];
    bf16x8 o;
    #pragma unroll
    for (int j = 0; j < 8; ++j) {
      float s = 0.f;
      #pragma unroll
      for (int i = 0; i < 10; ++i) s = fmaf(hv[i], dr[j * 10 + i], s);
      o[j] = (short)f2bf(fmaxf(s, 0.f));
    }
    *(bf16x8*)&sigb[((size_t)(mb * 16 + r)) * GG + kt * 2048 + tid * 8] = o;
  }
}

// ---------------- k_fsig: fused sig + 4-way split-K GEMM ----------------
__global__ __launch_bounds__(256) void k_fsig(const float* __restrict__ hg,
                                              const ushort* __restrict__ DinB,  // [4096][32]
                                              const ushort* __restrict__ Bm,    // DoutBT [512][4096]
                                              ushort* __restrict__ part) {      // [4][8192][512] bf16
  __shared__ __align__(16) short As[128 * 64];   // sig tile, XOR-64 layout, 16 KB
  __shared__ __align__(16) short Bs[128 * 64];   // DoutBT tile, XOR-64 layout, 16 KB
  int tid = threadIdx.x;
  int lane = tid & 63, wid = tid >> 6;
  int quad = lane >> 4, lr = lane & 15;
  int wm = wid >> 1, wn = wid & 1;
  int bid = blockIdx.x;
  int mb = bid & 63;
  int split = (bid >> 6) & 3;
  int nb = bid >> 8;                 // 0..3
  int k0 = split * 1024;

  const ushort* Bb = Bm + (size_t)nb * 128 * GG + k0;

  // Loop-invariant h fragments (sig-MFMA B operand): wave wid owns m rows
  // [wid*32, wid*32+32); lane layout B[col=lr][k=quad*8+j].
  bf16x8 haf[2];
  #pragma unroll
  for (int t = 0; t < 2; ++t) {
    int m = mb * 128 + wid * 32 + t * 16 + lr;
    const float* hr = hg + (size_t)m * 10;
    bf16x8 v;
    #pragma unroll
    for (int j = 0; j < 8; ++j) {
      int k = quad * 8 + j;
      v[j] = (k < 10) ? (short)f2bf(hr[k]) : (short)0;
    }
    haf[t] = v;
  }

  f32x4 acc[4][4];
  #pragma unroll
  for (int a = 0; a < 4; ++a)
    #pragma unroll
    for (int b = 0; b < 4; ++b) acc[a][b] = (f32x4){0.f, 0.f, 0.f, 0.f};
  const f32x4 zf = {0.f, 0.f, 0.f, 0.f};

  auto loadDin = [&](int it, bf16x8* dst) {
    #pragma unroll
    for (int gt = 0; gt < 4; ++gt)
      dst[gt] = *(const bf16x8*)&DinB[(size_t)(k0 + it * 64 + gt * 16 + lr) * 32 + quad * 8];
  };

  bf16x8 dinf[4];
  loadDin(0, dinf);

  for (int it = 0; it < 16; ++it) {
    if (it) __syncthreads();                     // WAR: As/Bs readers done
    // B stage (DoutBT) [128][64], XOR layout — drains at the mid barrier,
    // hidden under the sig phase.
    #pragma unroll
    for (int s4 = 0; s4 < 4; ++s4) {
      int s0 = (wid * 4 + s4) * 64;
      int s = s0 + lane;
      int r = s >> 3, pp = s & 7, p = pp ^ (r & 7);
      __builtin_amdgcn_global_load_lds(
          (const __attribute__((address_space(1))) u32*)(Bb + (size_t)r * GG + it * 64 + p * 8),
          (__attribute__((address_space(3))) u32*)(Bs + s0 * 8), 16, 0, 0);
    }
    // prefetch next iter's Din fragments (regs; waited on next iter)
    bf16x8 dnext[4];
    if (it < 15) loadDin(it + 1, dnext);
    // sig phase: 8 independent MFMAs first (pipelined) ...
    f32x4 sg[2][4];
    #pragma unroll
    for (int t = 0; t < 2; ++t)
      #pragma unroll
      for (int gt = 0; gt < 4; ++gt)
        sg[t][gt] = __builtin_amdgcn_mfma_f32_16x16x32_bf16(dinf[gt], haf[t], zf, 0, 0, 0);
    // ... then relu + packed convert + 8B swizzled stores.
    #pragma unroll
    for (int t = 0; t < 2; ++t) {
      int row = wid * 32 + t * 16 + lr;
      int rx = row & 7;
      #pragma unroll
      for (int gt = 0; gt < 4; ++gt) {
        f32x4 v = sg[t][gt];
        u32 lo = cvtpk(fmaxf(v[0], 0.f), fmaxf(v[1], 0.f));
        u32 hi = cvtpk(fmaxf(v[2], 0.f), fmaxf(v[3], 0.f));
        int p = (gt * 2 + (quad >> 1)) ^ rx;     // col-group XOR swizzle
        *(uint2*)&As[(row * 8 + p) * 8 + (quad & 1) * 4] = (uint2){lo, hi};
      }
    }
    #pragma unroll
    for (int gt = 0; gt < 4; ++gt) dinf[gt] = dnext[gt];
    __syncthreads();                             // As visible + B drained
    // main phase: 32 MFMA, both operands XOR-read
    #pragma unroll
    for (int ks = 0; ks < 2; ++ks) {
      bf16x8 af[4], bv[4];
      #pragma unroll
      for (int mt = 0; mt < 4; ++mt) {
        int ra = wm * 64 + mt * 16 + lr;
        int v = (ks * 4 + quad) ^ (ra & 7);
        af[mt] = *(const bf16x8*)&As[(ra * 8 + v) * 8];
      }
      #pragma unroll
      for (int nt = 0; nt < 4; ++nt) {
        int rb = wn * 64 + nt * 16 + lr;
        int v = (ks * 4 + quad) ^ (rb & 7);
        bv[nt] = *(const bf16x8*)&Bs[(rb * 8 + v) * 8];
      }
      #pragma unroll
      for (int mt = 0; mt < 4; ++mt)
        #pragma unroll
        for (int nt = 0; nt < 4; ++nt)
          acc[mt][nt] = __builtin_amdgcn_mfma_f32_16x16x32_bf16(af[mt], bv[nt], acc[mt][nt], 0, 0, 0);
    }
  }
  #pragma unroll
  for (int mt = 0; mt < 4; ++mt)
    #pragma unroll
    for (int nt = 0; nt < 4; ++nt) {
      int j = nb * 128 + wn * 64 + nt * 16 + lr;
      #pragma unroll
      for (int r = 0; r < 4; ++r) {
        int m = mb * 128 + wm * 64 + mt * 16 + quad * 4 + r;
        part[((size_t)split * 8192 + m) * 512 + j] = f2bf(acc[mt][nt][r]);
      }
    }
}

// ---------------- k_red: sum 4 bf16 splits, scatter into Abuf ----------------
__global__ __launch_bounds__(256) void k_red(const ushort* __restrict__ part,
                                             ushort* __restrict__ Abuf) {
  int t = blockIdx.x * 256 + threadIdx.x;            // 524288 threads, 8 el each
  int e0 = t * 8;
  int m = e0 >> 9, j0 = e0 & 511;
  bf16x8 a0 = *(const bf16x8*)(part + (size_t)m * 512 + j0);
  bf16x8 a1 = *(const bf16x8*)(part + (size_t)(8192 + m) * 512 + j0);
  bf16x8 a2 = *(const bf16x8*)(part + (size_t)(16384 + m) * 512 + j0);
  bf16x8 a3 = *(const bf16x8*)(part + (size_t)(24576 + m) * 512 + j0);
  float s[8];
  #pragma unroll
  for (int i = 0; i < 8; ++i)
    s[i] = (bf2f((ushort)a0[i]) + bf2f((ushort)a1[i])) +
           (bf2f((ushort)a2[i]) + bf2f((ushort)a3[i]));
  int btg = m >> 4, f = m & 15;
  #pragma unroll
  for (int jj = 0; jj < 8; ++jj) {
    int j = j0 + jj;
    if (j < GJ) {
      int l = (j >= 1) + (j >= 10) + (j >= 35) + (j >= 84) + (j >= 165) + (j >= 286);
      int o    = sel7(l, 0, 1, 10, 35, 84, 165, 286);
      int d    = sel7(l, 1, 3, 5, 7, 9, 11, 13);
      int Kp   = sel7(l, 64, 64, 128, 128, 192, 192, 256);
      int Aoff = sel7(l, 0, 32768, 131072, 458752, 917504, 1802240, 2883584);
      float rcpd = sel7f(l, 1.f, 1.f / 3.f, 0.2f, 1.f / 7.f, 1.f / 9.f,
                         1.f / 11.f, 1.f / 13.f);
      int jl = j - o;
      int u = (int)(((float)jl + 0.5f) * rcpd);
      int mB = jl - u * d;
      Abuf[(size_t)Aoff + ((size_t)btg * d + mB) * Kp + f * d + u] = f2bf(s[jj]);
    }
  }
}

// ---------------- k_mm2f: fallback combined GEMM (unchanged) ----------------
__global__ __launch_bounds__(256) void k_mm2f(const ushort* __restrict__ A,
                                              const ushort* __restrict__ Bm,
                                              ushort* __restrict__ Abuf) {
  __shared__ __align__(16) short Asb[2][128 * 64];
  __shared__ __align__(16) short Bsb[2][128 * 64];
  int tid = threadIdx.x;
  int lane = tid & 63, wid = tid >> 6;
  int quad = lane >> 4, lr = lane & 15;
  int wm = wid >> 1, wn = wid & 1;
  int bid = blockIdx.x;
  int mb = bid & 63, nb = bid >> 6;
  f32x4 acc[4][4];
  #pragma unroll
  for (int a = 0; a < 4; ++a)
    #pragma unroll
    for (int b = 0; b < 4; ++b) acc[a][b] = (f32x4){0.f, 0.f, 0.f, 0.f};
  const ushort* Ab = A + (size_t)mb * 128 * GG;
  const ushort* Bb = Bm + (size_t)nb * 128 * GG;
  auto stage = [&](int buf, int kc) {
    #pragma unroll
    for (int it = 0; it < 4; ++it) {
      int s0 = (wid * 4 + it) * 64;
      int s = s0 + lane;
      int r = s >> 3, pp = s & 7, p = pp ^ (r & 7);
      __builtin_amdgcn_global_load_lds(
          (const __attribute__((address_space(1))) u32*)(Ab + (size_t)r * GG + kc + p * 8),
          (__attribute__((address_space(3))) u32*)(&Asb[buf][s0 * 8]), 16, 0, 0);
    }
    #pragma unroll
    for (int it = 0; it < 4; ++it) {
      int s0 = (wid * 4 + it) * 64;
      int s = s0 + lane;
      int r = s >> 3, pp = s & 7, p = pp ^ (r & 7);
      __builtin_amdgcn_global_load_lds(
          (const __attribute__((address_space(1))) u32*)(Bb + (size_t)r * GG + kc + p * 8),
          (__attribute__((address_space(3))) u32*)(&Bsb[buf][s0 * 8]), 16, 0, 0);
    }
  };
  stage(0, 0);
  __syncthreads();
  for (int it = 0; it < 64; ++it) {
    int cur = it & 1;
    if (it < 63) stage(cur ^ 1, (it + 1) * 64);
    #pragma unroll
    for (int ks = 0; ks < 2; ++ks) {
      bf16x8 af[4], bvv[4];
      #pragma unroll
      for (int mt = 0; mt < 4; ++mt) {
        int ra = wm * 64 + mt * 16 + lr;
        int v = (ks * 4 + quad) ^ (ra & 7);
        af[mt] = *(const bf16x8*)&Asb[cur][(ra * 8 + v) * 8];
      }
      #pragma unroll
      for (int nt = 0; nt < 4; ++nt) {
        int rb = wn * 64 + nt * 16 + lr;
        int v = (ks * 4 + quad) ^ (rb & 7);
        bvv[nt] = *(const bf16x8*)&Bsb[cur][(rb * 8 + v) * 8];
      }
      #pragma unroll
      for (int mt = 0; mt < 4; ++mt)
        #pragma unroll
        for (int nt = 0; nt < 4; ++nt)
          acc[mt][nt] = __builtin_amdgcn_mfma_f32_16x16x32_bf16(af[mt], bvv[nt], acc[mt][nt], 0, 0, 0);
    }
    __syncthreads();
  }
  #pragma unroll
  for (int nt = 0; nt < 4; ++nt) {
    int j = nb * 128 + wn * 64 + nt * 16 + lr;
    if (j < GJ) {
      int l = (j >= 1) + (j >= 10) + (j >= 35) + (j >= 84) + (j >= 165) + (j >= 286);
      int o    = sel7(l, 0, 1, 10, 35, 84, 165, 286);
      int d    = sel7(l, 1, 3, 5, 7, 9, 11, 13);
      int Kp   = sel7(l, 64, 64, 128, 128, 192, 192, 256);
      int Aoff = sel7(l, 0, 32768, 131072, 458752, 917504, 1802240, 2883584);
      int jl = j - o;
      float rcpd = 1.0f / (float)d;
      int u = (int)(((float)jl + 0.5f) * rcpd);
      int mB = jl - u * d;
      #pragma unroll
      for (int mt = 0; mt < 4; ++mt)
        #pragma unroll
        for (int r = 0; r < 4; ++r) {
          int m = mb * 128 + wm * 64 + mt * 16 + quad * 4 + r;
          int btg = m >> 4, f = m & 15;
          Abuf[(size_t)Aoff + ((size_t)btg * d + mB) * Kp + f * d + u] =
              f2bf(acc[mt][nt][r]);
        }
    }
  }
}

// ---------------- k_batchX: per-l GEMMs + xg GEMM, single-buffer (unchanged) ----------------
__global__ __launch_bounds__(256) void k_batchX(const ushort* __restrict__ Abuf,
                                                const ushort* __restrict__ Bbuf,
                                                const float* __restrict__ x,
                                                const ushort* __restrict__ icoBx,
                                                ushort* __restrict__ trajbf,
                                                float* __restrict__ xg) {
  __shared__ __align__(16) short As[128 * 64];   // 16 KB
  __shared__ __align__(16) short Bs[128 * 64];   // 16 KB
  int bid = blockIdx.x;
  int tid = threadIdx.x;
  int lane = tid & 63, wid = tid >> 6;
  int quad = lane >> 4, lr = lane & 15;
  int wm = wid >> 1, wn = wid & 1;

  if (bid >= 1008) {
    // ---- xg path: 128x64 tile. A = x (f32 reg-staged -> bf16 LDS), B = icoBx.
    int mtile = bid - 1008;                          // 0..127
    f32x4 acc[4][2];
    #pragma unroll
    for (int a = 0; a < 4; ++a)
      #pragma unroll
      for (int b = 0; b < 2; ++b) acc[a][b] = (f32x4){0.f, 0.f, 0.f, 0.f};
    float xn[32];
    auto loadx = [&](int itk) {
      #pragma unroll
      for (int g = 0; g < 4; ++g) {
        int s = g * 256 + tid;
        int r = s >> 3, p8 = s & 7, p = p8 ^ (r & 7);
        const float* xr = x + (size_t)(mtile * 128 + r) * GJ;
        int j0 = itk * 64 + p * 8;
        #pragma unroll
        for (int jj = 0; jj < 8; ++jj) {
          int j = j0 + jj;
          xn[g * 8 + jj] = (j < GJ) ? xr[j] : 0.f;
        }
      }
    };
    auto writex = [&]() {
      #pragma unroll
      for (int g = 0; g < 4; ++g) {
        int s = g * 256 + tid;
        bf16x8 v8;
        #pragma unroll
        for (int jj = 0; jj < 8; ++jj) v8[jj] = (short)f2bf(xn[g * 8 + jj]);
        *(bf16x8*)&As[s * 8] = v8;
      }
    };
    auto stageBx = [&](int kc) {
      #pragma unroll
      for (int it = 0; it < 2; ++it) {
        int s0 = (wid * 2 + it) * 64;
        int s = s0 + lane;
        int r = s >> 3, p8 = s & 7, p = p8 ^ (r & 7);
        const ushort* gb = icoBx + (size_t)r * JP + kc + p * 8;
        __builtin_amdgcn_global_load_lds(
            (const __attribute__((address_space(1))) u32*)gb,
            (__attribute__((address_space(3))) u32*)(Bs + s0 * 8), 16, 0, 0);
      }
    };
    loadx(0); writex(); stageBx(0);
    __syncthreads();
    for (int it = 0; it < 8; ++it) {
      if (it < 7) loadx(it + 1);           // T14: issue next loads before MFMAs
      #pragma unroll
      for (int ks = 0; ks < 2; ++ks) {
        bf16x8 af[4], bv[2];
        #pragma unroll
        for (int mt = 0; mt < 4; ++mt) {
          int ra = wm * 64 + mt * 16 + lr;
          int v = (ks * 4 + quad) ^ (ra & 7);
          af[mt] = *(const bf16x8*)&As[(ra * 8 + v) * 8];
        }
        #pragma unroll
        for (int nt = 0; nt < 2; ++nt) {
          int rb = wn * 32 + nt * 16 + lr;
          int v = (ks * 4 + quad) ^ (rb & 7);
          bv[nt] = *(const bf16x8*)&Bs[(rb * 8 + v) * 8];
        }
        #pragma unroll
        for (int mt = 0; mt < 4; ++mt)
          #pragma unroll
          for (int nt = 0; nt < 2; ++nt)
            acc[mt][nt] = __builtin_amdgcn_mfma_f32_16x16x32_bf16(af[mt], bv[nt], acc[mt][nt], 0, 0, 0);
      }
      if (it < 7) {
        __syncthreads();                   // everyone done reading As/Bs
        writex();                          // convert + ds_write next A
        stageBx((it + 1) * 64);            // issue next B -> LDS
        __syncthreads();                   // drains vmcnt + LDS writes
      }
    }
    #pragma unroll
    for (int mt = 0; mt < 4; ++mt)
      #pragma unroll
      for (int nt = 0; nt < 2; ++nt) {
        int i = wn * 32 + nt * 16 + lr;
        if (i < NICO) {
          #pragma unroll
          for (int r = 0; r < 4; ++r) {
            int row = mtile * 128 + wm * 64 + mt * 16 + quad * 4 + r;
            xg[(size_t)row * NICO + i] = acc[mt][nt][r];
          }
        }
      }
    return;
  }

  // ---- per-l path: 128x128 tile, single-buffer.
  f32x4 acc[4][4];
  #pragma unroll
  for (int a = 0; a < 4; ++a)
    #pragma unroll
    for (int b = 0; b < 4; ++b) acc[a][b] = (f32x4){0.f, 0.f, 0.f, 0.f};

  int l = (bid >= 4) + (bid >= 28) + (bid >= 88) + (bid >= 200) +
          (bid >= 380) + (bid >= 644);
  int bbase = sel7(l, 0, 4, 28, 88, 200, 380, 644);
  int d     = sel7(l, 1, 3, 5, 7, 9, 11, 13);
  int Kp    = sel7(l, 64, 64, 128, 128, 192, 192, 256);
  int o     = sel7(l, 0, 1, 10, 35, 84, 165, 286);
  int Aoff  = sel7(l, 0, 32768, 131072, 458752, 917504, 1802240, 2883584);
  int Boff  = sel7(l, 0, 4096, 16384, 57344, 114688, 225280, 360448);
  int ntc   = sel7(l, 1, 2, 3, 4, 5, 6, 7);         // ceil(64d/128)
  float rcpntc = sel7f(l, 1.f, 0.5f, 1.f / 3.f, 0.25f, 0.2f, 1.f / 6.f, 1.f / 7.f);
  float rcpd   = sel7f(l, 1.f, 1.f / 3.f, 0.2f, 1.f / 7.f, 1.f / 9.f,
                       1.f / 11.f, 1.f / 13.f);
  int t = bid - bbase;
  int mtile = (int)(((float)t + 0.5f) * rcpntc);    // exact (margin >> eps)
  int ntile = t - mtile * ntc;
  int Nl = 64 * d;

  const ushort* Ab = Abuf + Aoff + (size_t)mtile * 128 * Kp;
  const ushort* Bb = Bbuf + Boff + (size_t)ntile * 128 * Kp;

  auto stage = [&](int kc) {
    #pragma unroll
    for (int it = 0; it < 4; ++it) {
      int s0 = (wid * 4 + it) * 64;
      int s = s0 + lane;
      int r = s >> 3, pp = s & 7, p = pp ^ (r & 7);
      __builtin_amdgcn_global_load_lds(
          (const __attribute__((address_space(1))) u32*)(Ab + (size_t)r * Kp + kc + p * 8),
          (__attribute__((address_space(3))) u32*)(As + s0 * 8), 16, 0, 0);
    }
    #pragma unroll
    for (int it = 0; it < 4; ++it) {
      int s0 = (wid * 4 + it) * 64;
      int s = s0 + lane;
      int r = s >> 3, pp = s & 7, p = pp ^ (r & 7);
      __builtin_amdgcn_global_load_lds(
          (const __attribute__((address_space(1))) u32*)(Bb + (size_t)r * Kp + kc + p * 8),
          (__attribute__((address_space(3))) u32*)(Bs + s0 * 8), 16, 0, 0);
    }
  };

  int nIter = Kp >> 6;                               // 1..4
  for (int it = 0; it < nIter; ++it) {
    if (it) __syncthreads();                         // WAR on LDS
    stage(it * 64);
    __syncthreads();                                 // drains vmcnt
    #pragma unroll
    for (int ks = 0; ks < 2; ++ks) {
      bf16x8 af[4], bv[4];
      #pragma unroll
      for (int mt = 0; mt < 4; ++mt) {
        int ra = wm * 64 + mt * 16 + lr;
        int v = (ks * 4 + quad) ^ (ra & 7);
        af[mt] = *(const bf16x8*)&As[(ra * 8 + v) * 8];
      }
      #pragma unroll
      for (int nt = 0; nt < 4; ++nt) {
        int rb = wn * 64 + nt * 16 + lr;
        int v = (ks * 4 + quad) ^ (rb & 7);
        bv[nt] = *(const bf16x8*)&Bs[(rb * 8 + v) * 8];
      }
      #pragma unroll
      for (int mt = 0; mt < 4; ++mt)
        #pragma unroll
        for (int nt = 0; nt < 4; ++nt)
          acc[mt][nt] = __builtin_amdgcn_mfma_f32_16x16x32_bf16(af[mt], bv[nt], acc[mt][nt], 0, 0, 0);
    }
  }
  // kappa-permuted scatter: index o + m*d + v (consecutive v -> contiguous)
  #pragma unroll
  for (int nt = 0; nt < 4; ++nt) {
    int Ncol = ntile * 128 + wn * 64 + nt * 16 + lr;
    if (Ncol < Nl) {
      int g2 = (int)(((float)Ncol + 0.5f) * rcpd);
      int v = Ncol - g2 * d;
      #pragma unroll
      for (int mt = 0; mt < 4; ++mt)
        #pragma unroll
        for (int r = 0; r < 4; ++r) {
          int Mrow = mtile * 128 + wm * 64 + mt * 16 + quad * 4 + r;
          int bt = (int)(((float)Mrow + 0.5f) * rcpd);
          int m = Mrow - bt * d;
          trajbf[(size_t)(bt * 64 + g2) * JP + o + m * d + v] = f2bf(acc[mt][nt][r]);
        }
    }
  }
}

// ---------------- k_icoT: trajo = trajbf . icoB^T, single-buffer (unchanged) ----------------
__global__ __launch_bounds__(256) void k_icoT(const ushort* __restrict__ trajbf,
                                              const ushort* __restrict__ icoB,
                                              float* __restrict__ trajo) {
  __shared__ __align__(16) short As[128 * 64];   // 16 KB
  __shared__ __align__(16) short Bs[64 * 64];    // 8 KB
  int mtile = blockIdx.x;                         // 0..255
  int tid = threadIdx.x;
  int lane = tid & 63, wid = tid >> 6;
  int quad = lane >> 4, lr = lane & 15;
  int wm = wid >> 1, wn = wid & 1;
  f32x4 acc[4][2];
  #pragma unroll
  for (int a = 0; a < 4; ++a)
    #pragma unroll
    for (int b = 0; b < 2; ++b) acc[a][b] = (f32x4){0.f, 0.f, 0.f, 0.f};

  auto stage = [&](int kc) {
    #pragma unroll
    for (int it = 0; it < 4; ++it) {
      int s0 = (wid * 4 + it) * 64;
      int s = s0 + lane;
      int r = s >> 3, p8 = s & 7, p = p8 ^ (r & 7);
      const ushort* ga = trajbf + (size_t)(mtile * 128 + r) * JP + kc + p * 8;
      __builtin_amdgcn_global_load_lds(
          (const __attribute__((address_space(1))) u32*)ga,
          (__attribute__((address_space(3))) u32*)(As + s0 * 8), 16, 0, 0);
    }
    #pragma unroll
    for (int it = 0; it < 2; ++it) {
      int s0 = (wid * 2 + it) * 64;
      int s = s0 + lane;
      int r = s >> 3, p8 = s & 7, p = p8 ^ (r & 7);
      const ushort* gb = icoB + (size_t)r * JP + kc + p * 8;
      __builtin_amdgcn_global_load_lds(
          (const __attribute__((address_space(1))) u32*)gb,
          (__attribute__((address_space(3))) u32*)(Bs + s0 * 8), 16, 0, 0);
    }
  };

  for (int it = 0; it < 8; ++it) {
    if (it) __syncthreads();                         // WAR on LDS
    stage(it * 64);
    __syncthreads();                                 // drains vmcnt
    #pragma unroll
    for (int ks = 0; ks < 2; ++ks) {
      bf16x8 af[4], bv[2];
      #pragma unroll
      for (int mt = 0; mt < 4; ++mt) {
        int ra = wm * 64 + mt * 16 + lr;
        int v = (ks * 4 + quad) ^ (ra & 7);
        af[mt] = *(const bf16x8*)&As[(ra * 8 + v) * 8];
      }
      #pragma unroll
      for (int nt = 0; nt < 2; ++nt) {
        int rb = wn * 32 + nt * 16 + lr;
        int v = (ks * 4 + quad) ^ (rb & 7);
        bv[nt] = *(const bf16x8*)&Bs[(rb * 8 + v) * 8];
      }
      #pragma unroll
      for (int mt = 0; mt < 4; ++mt)
        #pragma unroll
        for (int nt = 0; nt < 2; ++nt)
          acc[mt][nt] = __builtin_amdgcn_mfma_f32_16x16x32_bf16(af[mt], bv[nt], acc[mt][nt], 0, 0, 0);
    }
  }
  #pragma unroll
  for (int mt = 0; mt < 4; ++mt)
    #pragma unroll
    for (int nt = 0; nt < 2; ++nt) {
      int i = wn * 32 + nt * 16 + lr;
      if (i < NICO) {
        #pragma unroll
        for (int r = 0; r < 4; ++r) {
          int row = mtile * 128 + wm * 64 + mt * 16 + quad * 4 + r;
          trajo[(size_t)row * NICO + i] = acc[mt][nt][r];
        }
      }
    }
}

extern "C" void kernel_launch(void* const* d_in, const int* in_sizes, int n_in,
                              void* d_out, int out_size, void* d_ws, size_t ws_size,
                              hipStream_t stream) {
  const float *x = nullptr, *traj = nullptr, *w1s = nullptr, *w1v = nullptr;
  const float *Din = nullptr, *Dout = nullptr, *ico = nullptr;
  W7 w2{};
  for (int i = 0; i < n_in; ++i) {
    const float* p = (const float*)d_in[i];
    switch (in_sizes[i]) {
      case 7454720: x = p; break;
      case 5120:    traj = p; break;
      case 16:      w1s = p; break;
      case 144:     w1v = p; break;
      case 40960:   Din = p; break;
      case 1863680: Dout = p; break;
      case 27300:   ico = p; break;
      case 1024:    w2.p[0] = p; break;
      case 9216:    w2.p[1] = p; break;
      case 25600:   w2.p[2] = p; break;
      case 50176:   w2.p[3] = p; break;
      case 82944:   w2.p[4] = p; break;
      case 123904:  w2.p[5] = p; break;
      case 173056:  w2.p[6] = p; break;
      default: break;
    }
  }
  // ws layout (bytes):
  //   h       @ 0            (327,680)
  //   DoutBT  @ 327,680      (4,194,304)
  //   icoB    @ 4,521,984    (65,536)   [kappa-permuted]
  //   icoBx   @ 4,587,520    (65,536)   [j-order, for xg]
  //   Abuf    @ 4,653,056    (9,175,040)
  //   Bbuf    @ 13,828,096   (1,146,880)
  //   sigb    @ 14,974,976   (67,108,864)
  //     trajbf aliases sigb[0, 33.5MB)
  //     part (4 splits, 33.5MB) aliases sigb[33.5MB, 67MB) — consumed by
  //     k_red before k_batchX writes trajbf; regions are disjoint anyway.
  //   DinB    @ 82,083,840   (262,144)  [main path only]
  char* wsb = (char*)d_ws;
  float*  h       = (float*)wsb;
  ushort* DoutBT  = (ushort*)(wsb + 327680);
  ushort* icoB    = (ushort*)(wsb + 4521984);
  ushort* icoBx   = (ushort*)(wsb + 4587520);
  ushort* Abuf    = (ushort*)(wsb + 4653056);
  ushort* Bbuf    = (ushort*)(wsb + 13828096);
  ushort* sigb    = (ushort*)(wsb + 14974976);
  ushort* trajbf  = sigb;
  ushort* part    = (ushort*)(wsb + 48529408);
  ushort* DinB    = (ushort*)(wsb + 82083840);
  float* xg    = (float*)d_out;
  float* trajo = (float*)d_out + 983040;

  bool mainpath = ws_size >= 115638272ULL;

  k_pre<<<dim3(5584), dim3(256), 0, stream>>>(traj, w1s, w1v, ico, Dout, Din,
                                              w2, h, icoB, icoBx, DoutBT, Abuf,
                                              Bbuf, mainpath ? DinB : nullptr);
  if (mainpath) {
    k_fsig<<<dim3(1024), dim3(256), 0, stream>>>(h, DinB, DoutBT, part);
    k_red <<<dim3(2048), dim3(256), 0, stream>>>(part, Abuf);
  } else {
    k_sig<<<dim3(2, 512), dim3(256), 0, stream>>>(h, Din, sigb);
    k_mm2f<<<dim3(256),  dim3(256), 0, stream>>>(sigb, DoutBT, Abuf);
  }
  k_batchX<<<dim3(1136), dim3(256), 0, stream>>>(Abuf, Bbuf, x, icoBx, trajbf, xg);
  k_icoT  <<<dim3(256),  dim3(256), 0, stream>>>(trajbf, icoB, trajo);
}

// Round 8
// 232.519 us; speedup vs baseline: 1.0099x; 1.0099x over previous
//
#include <hip/hip_runtime.h>
#include <math.h>

// EquiGroupSamplingIco — round 18: co-schedule xg with k_fsig.
// Seven rounds flat at ~234 -> the cost is serialized latency-bound
// STRETCHES, not inner loops. k_batchX has been 48-51us in every round, and
// in every round its tail was the same 128 xg blocks (8 serial iters,
// guarded scalar x loads, <=half the machine busy). The xg GEMM depends only
// on x + icoBx (ready after k_pre) — NOT on k_fsig/k_red.
// Fix:
//  - xg blocks moved into k_fsig's grid (bid>=1024): latency-bound xg blocks
//    fill k_fsig's barrier gaps (MFMA/VALU co-schedule across blocks).
//  - k_batchX (main path) = per-l only, 1008 short blocks.
//  - xg loads: j<GJ guard hoisted to the last K-step only.
// Fallback path unchanged (k_batchX keeps its xg branch, grid 1136).

#define NBT  512
#define F8c  16
#define F2c  64
#define GJ   455
#define GG   4096
#define NICO 60
#define JP   512      // padded j for trajbf / icoB

typedef short bf16x8 __attribute__((ext_vector_type(8)));
typedef float f32x4  __attribute__((ext_vector_type(4)));
typedef unsigned short u16x4 __attribute__((ext_vector_type(4)));
typedef unsigned int u32;
typedef unsigned short ushort;

struct W7 { const float* p[7]; };

__device__ __forceinline__ ushort f2bf(float f) {
  u32 u = __float_as_uint(f);
  return (ushort)((u + 0x7fffu + ((u >> 16) & 1u)) >> 16);   // RNE
}
__device__ __forceinline__ float bf2f(ushort v) {
  return __uint_as_float(((u32)v) << 16);
}
__device__ __forceinline__ u32 cvtpk(float lo, float hi) {   // 2xf32 -> 2xbf16 (RNE)
  u32 r;
  asm("v_cvt_pk_bf16_f32 %0, %1, %2" : "=v"(r) : "v"(lo), "v"(hi));
  return r;
}

__device__ __forceinline__ int sel7(int l, int a0, int a1, int a2, int a3,
                                    int a4, int a5, int a6) {
  int r = a6;
  r = (l == 5) ? a5 : r; r = (l == 4) ? a4 : r; r = (l == 3) ? a3 : r;
  r = (l == 2) ? a2 : r; r = (l == 1) ? a1 : r; r = (l == 0) ? a0 : r;
  return r;
}
__device__ __forceinline__ float sel7f(int l, float a0, float a1, float a2,
                                       float a3, float a4, float a5, float a6) {
  float r = a6;
  r = (l == 5) ? a5 : r; r = (l == 4) ? a4 : r; r = (l == 3) ? a3 : r;
  r = (l == 2) ? a2 : r; r = (l == 1) ? a1 : r; r = (l == 0) ? a0 : r;
  return r;
}

// ---------------- k_pre: fused preprocessing (unchanged) ----------------
__global__ __launch_bounds__(256) void k_pre(const float* __restrict__ traj,
                                             const float* __restrict__ w1s,
                                             const float* __restrict__ w1v,
                                             const float* __restrict__ ico,
                                             const float* __restrict__ Dout,
                                             const float* __restrict__ Din,
                                             W7 w2,
                                             float* __restrict__ h,
                                             ushort* __restrict__ icoB,
                                             ushort* __restrict__ icoBx,
                                             ushort* __restrict__ DoutBT,
                                             ushort* __restrict__ Abuf,
                                             ushort* __restrict__ Bbuf,
                                             ushort* __restrict__ DinB) {
  __shared__ float t[64][65];
  int b = blockIdx.x, tid = threadIdx.x;
  if (b < 2240) {
    ((uint4*)Abuf)[b * 256 + tid] = (uint4){0, 0, 0, 0};
  } else if (b < 2752) {
    int b2 = b - 2240;
    int jt = b2 & 7, kt = b2 >> 3;
    int tx = tid & 63, ty = tid >> 6;
    #pragma unroll
    for (int i = 0; i < 16; ++i) {
      int r = i * 4 + ty, j = jt * 64 + tx;
      t[r][tx] = (j < GJ) ? Dout[(size_t)(kt * 64 + r) * GJ + j] : 0.f;
    }
    __syncthreads();
    #pragma unroll
    for (int i = 0; i < 16; ++i) {
      int jl = i * 4 + ty;
      DoutBT[(size_t)(jt * 64 + jl) * GG + kt * 64 + tx] = f2bf(t[tx][jl]);
    }
  } else if (b < 4992) {
    int ee = (b - 2752) * 256 + tid;
    if (ee < 573440) {
      int l = (ee >= 4096) + (ee >= 16384) + (ee >= 57344) + (ee >= 114688) +
              (ee >= 225280) + (ee >= 360448);
      int base = sel7(l, 0, 4096, 16384, 57344, 114688, 225280, 360448);
      int d    = sel7(l, 1, 3, 5, 7, 9, 11, 13);
      int Kp   = sel7(l, 64, 64, 128, 128, 192, 192, 256);
      int local = ee - base;
      int row = local / Kp, kcol = local - row * Kp;
      int g2 = row / d, v = row - g2 * d;
      ushort val = 0;
      if (kcol < 16 * d) {
        int f = kcol / d, u = kcol - f * d;
        const float* wl = w2.p[l];
        float scl = rsqrtf(16.f * (float)d);
        val = f2bf(wl[(((size_t)f * 64 + g2) * d + u) * d + v] * scl);
      }
      Bbuf[ee] = val;
    }
  } else if (b < 5312) {
    int idx = (b - 4992) * 256 + tid;
    if (idx < NBT * 160) {
      int bt = idx / 160, r = idx % 160, c = r / 10, i = r % 10;
      const float* tr = traj + bt * 10;
      float val;
      if (i == 0) {
        val = tr[9] * w1s[c];
      } else {
        int k = i - 1, v = k / 3, m = k % 3;
        float s = 0.f;
        #pragma unroll
        for (int u = 0; u < 3; ++u) s = fmaf(tr[u * 3 + m], w1v[c * 9 + u * 3 + v], s);
        val = s * 0.57735026918962576f;
      }
      h[idx] = val;
    }
  } else if (b < 5440) {
    // icoB, kappa-permuted: icoB[i][o + m*d + v] = ico[i][o + v*d + m]
    int e = (b - 5312) * 256 + tid;   // 32768
    int i = e >> 9, k = e & 511;
    ushort val = 0;
    if (i < NICO && k < GJ) {
      int l = (k >= 1) + (k >= 10) + (k >= 35) + (k >= 84) + (k >= 165) + (k >= 286);
      int o = sel7(l, 0, 1, 10, 35, 84, 165, 286);
      int d = sel7(l, 1, 3, 5, 7, 9, 11, 13);
      float rcpd = sel7f(l, 1.f, 1.f / 3.f, 0.2f, 1.f / 7.f, 1.f / 9.f,
                         1.f / 11.f, 1.f / 13.f);
      int local = k - o;
      int m = (int)(((float)local + 0.5f) * rcpd);   // exact (margin >> eps)
      int v = local - m * d;
      val = f2bf(ico[i * GJ + o + v * d + m]);
    }
    icoB[e] = val;
  } else if (b < 5568) {
    // icoBx, original j-order (for the xg GEMM: x is in j-order)
    int e = (b - 5440) * 256 + tid;   // 32768
    int i = e >> 9, j = e & 511;
    icoBx[e] = (i < NICO && j < GJ) ? f2bf(ico[i * GJ + j]) : (ushort)0;
  } else {
    // DinB: [4096 g][32 k] bf16, k<10 from Din, rest 0. Main path only.
    if (DinB != nullptr) {
      int g = (b - 5568) * 256 + tid;   // 4096
      const float* dr = Din + (size_t)g * 10;
      #pragma unroll
      for (int k = 0; k < 32; ++k)
        DinB[(size_t)g * 32 + k] = (k < 10) ? f2bf(dr[k]) : (ushort)0;
    }
  }
}

// ---------------- k_sig (fallback path only, unchanged) ----------------
__global__ __launch_bounds__(256) void k_sig(const float* __restrict__ h,
                                             const float* __restrict__ Din,
                                             ushort* __restrict__ sigb) {
  __shared__ float hs[160];
  int tid = threadIdx.x;
  int mb = blockIdx.y;
  int kt = blockIdx.x;           // 0..1
  if (tid < 160) hs[tid] = h[mb * 160 + tid];
  float dr[80];
  const float4* dp = (const float4*)(Din + (size_t)(kt * 2048 + tid * 8) * 10);
  #pragma unroll
  for (int q = 0; q < 20; ++q) {
    float4 v = dp[q];
    dr[q * 4 + 0] = v.x; dr[q * 4 + 1] = v.y; dr[q * 4 + 2] = v.z; dr[q * 4 + 3] = v.w;
  }
  __syncthreads();
  #pragma unroll
  for (int r = 0; r < 16; ++r) {
    float hv[10];
    #pragma unroll
    for (int i = 0; i < 10; ++i) hv[i] = hs[r * 10 + i];
    bf16x8 o;
    #pragma unroll
    for (int j = 0; j < 8; ++j) {
      float s = 0.f;
      #pragma unroll
      for (int i = 0; i < 10; ++i) s = fmaf(hv[i], dr[j * 10 + i], s);
      o[j] = (short)f2bf(fmaxf(s, 0.f));
    }
    *(bf16x8*)&sigb[((size_t)(mb * 16 + r)) * GG + kt * 2048 + tid * 8] = o;
  }
}

// ---------------- k_fsig: fused sig + 4-way split-K GEMM, + xg blocks ----------------
// bid < 1024: fused sig GEMM (unchanged R17). bid >= 1024: xg GEMM (128x64
// tile, independent of the sig chain — co-runs to fill latency gaps).
__global__ __launch_bounds__(256) void k_fsig(const float* __restrict__ hg,
                                              const ushort* __restrict__ DinB,  // [4096][32]
                                              const ushort* __restrict__ Bm,    // DoutBT [512][4096]
                                              ushort* __restrict__ part,        // [4][8192][512] bf16
                                              const float* __restrict__ x,
                                              const ushort* __restrict__ icoBx,
                                              float* __restrict__ xg) {
  __shared__ __align__(16) short As[128 * 64];   // 16 KB (both branches)
  __shared__ __align__(16) short Bs[128 * 64];   // 16 KB
  int tid = threadIdx.x;
  int lane = tid & 63, wid = tid >> 6;
  int quad = lane >> 4, lr = lane & 15;
  int wm = wid >> 1, wn = wid & 1;
  int bid = blockIdx.x;

  if (bid >= 1024) {
    // ---- xg path: 128x64 tile. A = x (f32 reg-staged -> bf16 LDS), B = icoBx.
    int mtile = bid - 1024;                          // 0..127
    f32x4 acc[4][2];
    #pragma unroll
    for (int a = 0; a < 4; ++a)
      #pragma unroll
      for (int b = 0; b < 2; ++b) acc[a][b] = (f32x4){0.f, 0.f, 0.f, 0.f};
    float xn[32];
    auto loadx = [&](int itk) {
      if (itk < 7) {                       // itk*64+p*8+7 <= 447 < GJ: no guard
        #pragma unroll
        for (int g = 0; g < 4; ++g) {
          int s = g * 256 + tid;
          int r = s >> 3, p8 = s & 7, p = p8 ^ (r & 7);
          const float* xr = x + (size_t)(mtile * 128 + r) * GJ + itk * 64 + p * 8;
          #pragma unroll
          for (int jj = 0; jj < 8; ++jj) xn[g * 8 + jj] = xr[jj];
        }
      } else {
        #pragma unroll
        for (int g = 0; g < 4; ++g) {
          int s = g * 256 + tid;
          int r = s >> 3, p8 = s & 7, p = p8 ^ (r & 7);
          const float* xr = x + (size_t)(mtile * 128 + r) * GJ;
          int j0 = itk * 64 + p * 8;
          #pragma unroll
          for (int jj = 0; jj < 8; ++jj) {
            int j = j0 + jj;
            xn[g * 8 + jj] = (j < GJ) ? xr[j] : 0.f;
          }
        }
      }
    };
    auto writex = [&]() {
      #pragma unroll
      for (int g = 0; g < 4; ++g) {
        int s = g * 256 + tid;
        bf16x8 v8;
        #pragma unroll
        for (int jj = 0; jj < 8; ++jj) v8[jj] = (short)f2bf(xn[g * 8 + jj]);
        *(bf16x8*)&As[s * 8] = v8;
      }
    };
    auto stageBx = [&](int kc) {
      #pragma unroll
      for (int it = 0; it < 2; ++it) {
        int s0 = (wid * 2 + it) * 64;
        int s = s0 + lane;
        int r = s >> 3, p8 = s & 7, p = p8 ^ (r & 7);
        const ushort* gb = icoBx + (size_t)r * JP + kc + p * 8;
        __builtin_amdgcn_global_load_lds(
            (const __attribute__((address_space(1))) u32*)gb,
            (__attribute__((address_space(3))) u32*)(Bs + s0 * 8), 16, 0, 0);
      }
    };
    loadx(0); writex(); stageBx(0);
    __syncthreads();
    for (int it = 0; it < 8; ++it) {
      if (it < 7) loadx(it + 1);           // T14: issue next loads before MFMAs
      #pragma unroll
      for (int ks = 0; ks < 2; ++ks) {
        bf16x8 af[4], bv[2];
        #pragma unroll
        for (int mt = 0; mt < 4; ++mt) {
          int ra = wm * 64 + mt * 16 + lr;
          int v = (ks * 4 + quad) ^ (ra & 7);
          af[mt] = *(const bf16x8*)&As[(ra * 8 + v) * 8];
        }
        #pragma unroll
        for (int nt = 0; nt < 2; ++nt) {
          int rb = wn * 32 + nt * 16 + lr;
          int v = (ks * 4 + quad) ^ (rb & 7);
          bv[nt] = *(const bf16x8*)&Bs[(rb * 8 + v) * 8];
        }
        #pragma unroll
        for (int mt = 0; mt < 4; ++mt)
          #pragma unroll
          for (int nt = 0; nt < 2; ++nt)
            acc[mt][nt] = __builtin_amdgcn_mfma_f32_16x16x32_bf16(af[mt], bv[nt], acc[mt][nt], 0, 0, 0);
      }
      if (it < 7) {
        __syncthreads();                   // everyone done reading As/Bs
        writex();                          // convert + ds_write next A
        stageBx((it + 1) * 64);            // issue next B -> LDS
        __syncthreads();                   // drains vmcnt + LDS writes
      }
    }
    #pragma unroll
    for (int mt = 0; mt < 4; ++mt)
      #pragma unroll
      for (int nt = 0; nt < 2; ++nt) {
        int i = wn * 32 + nt * 16 + lr;
        if (i < NICO) {
          #pragma unroll
          for (int r = 0; r < 4; ++r) {
            int row = mtile * 128 + wm * 64 + mt * 16 + quad * 4 + r;
            xg[(size_t)row * NICO + i] = acc[mt][nt][r];
          }
        }
      }
    return;
  }

  // ---- fused sig + GEMM path (unchanged R17) ----
  int mb = bid & 63;
  int split = (bid >> 6) & 3;
  int nb = bid >> 8;                 // 0..3
  int k0 = split * 1024;

  const ushort* Bb = Bm + (size_t)nb * 128 * GG + k0;

  bf16x8 haf[2];
  #pragma unroll
  for (int t = 0; t < 2; ++t) {
    int m = mb * 128 + wid * 32 + t * 16 + lr;
    const float* hr = hg + (size_t)m * 10;
    bf16x8 v;
    #pragma unroll
    for (int j = 0; j < 8; ++j) {
      int k = quad * 8 + j;
      v[j] = (k < 10) ? (short)f2bf(hr[k]) : (short)0;
    }
    haf[t] = v;
  }

  f32x4 acc[4][4];
  #pragma unroll
  for (int a = 0; a < 4; ++a)
    #pragma unroll
    for (int b = 0; b < 4; ++b) acc[a][b] = (f32x4){0.f, 0.f, 0.f, 0.f};
  const f32x4 zf = {0.f, 0.f, 0.f, 0.f};

  auto loadDin = [&](int it, bf16x8* dst) {
    #pragma unroll
    for (int gt = 0; gt < 4; ++gt)
      dst[gt] = *(const bf16x8*)&DinB[(size_t)(k0 + it * 64 + gt * 16 + lr) * 32 + quad * 8];
  };

  bf16x8 dinf[4];
  loadDin(0, dinf);

  for (int it = 0; it < 16; ++it) {
    if (it) __syncthreads();                     // WAR: As/Bs readers done
    #pragma unroll
    for (int s4 = 0; s4 < 4; ++s4) {
      int s0 = (wid * 4 + s4) * 64;
      int s = s0 + lane;
      int r = s >> 3, pp = s & 7, p = pp ^ (r & 7);
      __builtin_amdgcn_global_load_lds(
          (const __attribute__((address_space(1))) u32*)(Bb + (size_t)r * GG + it * 64 + p * 8),
          (__attribute__((address_space(3))) u32*)(Bs + s0 * 8), 16, 0, 0);
    }
    bf16x8 dnext[4];
    if (it < 15) loadDin(it + 1, dnext);
    f32x4 sg[2][4];
    #pragma unroll
    for (int t = 0; t < 2; ++t)
      #pragma unroll
      for (int gt = 0; gt < 4; ++gt)
        sg[t][gt] = __builtin_amdgcn_mfma_f32_16x16x32_bf16(dinf[gt], haf[t], zf, 0, 0, 0);
    #pragma unroll
    for (int t = 0; t < 2; ++t) {
      int row = wid * 32 + t * 16 + lr;
      int rx = row & 7;
      #pragma unroll
      for (int gt = 0; gt < 4; ++gt) {
        f32x4 v = sg[t][gt];
        u32 lo = cvtpk(fmaxf(v[0], 0.f), fmaxf(v[1], 0.f));
        u32 hi = cvtpk(fmaxf(v[2], 0.f), fmaxf(v[3], 0.f));
        int p = (gt * 2 + (quad >> 1)) ^ rx;     // col-group XOR swizzle
        *(uint2*)&As[(row * 8 + p) * 8 + (quad & 1) * 4] = (uint2){lo, hi};
      }
    }
    #pragma unroll
    for (int gt = 0; gt < 4; ++gt) dinf[gt] = dnext[gt];
    __syncthreads();                             // As visible + B drained
    #pragma unroll
    for (int ks = 0; ks < 2; ++ks) {
      bf16x8 af[4], bv[4];
      #pragma unroll
      for (int mt = 0; mt < 4; ++mt) {
        int ra = wm * 64 + mt * 16 + lr;
        int v = (ks * 4 + quad) ^ (ra & 7);
        af[mt] = *(const bf16x8*)&As[(ra * 8 + v) * 8];
      }
      #pragma unroll
      for (int nt = 0; nt < 4; ++nt) {
        int rb = wn * 64 + nt * 16 + lr;
        int v = (ks * 4 + quad) ^ (rb & 7);
        bv[nt] = *(const bf16x8*)&Bs[(rb * 8 + v) * 8];
      }
      #pragma unroll
      for (int mt = 0; mt < 4; ++mt)
        #pragma unroll
        for (int nt = 0; nt < 4; ++nt)
          acc[mt][nt] = __builtin_amdgcn_mfma_f32_16x16x32_bf16(af[mt], bv[nt], acc[mt][nt], 0, 0, 0);
    }
  }
  #pragma unroll
  for (int mt = 0; mt < 4; ++mt)
    #pragma unroll
    for (int nt = 0; nt < 4; ++nt) {
      int j = nb * 128 + wn * 64 + nt * 16 + lr;
      #pragma unroll
      for (int r = 0; r < 4; ++r) {
        int m = mb * 128 + wm * 64 + mt * 16 + quad * 4 + r;
        part[((size_t)split * 8192 + m) * 512 + j] = f2bf(acc[mt][nt][r]);
      }
    }
}

// ---------------- k_red: sum 4 bf16 splits, scatter into Abuf (unchanged) ----------------
__global__ __launch_bounds__(256) void k_red(const ushort* __restrict__ part,
                                             ushort* __restrict__ Abuf) {
  int t = blockIdx.x * 256 + threadIdx.x;            // 524288 threads, 8 el each
  int e0 = t * 8;
  int m = e0 >> 9, j0 = e0 & 511;
  bf16x8 a0 = *(const bf16x8*)(part + (size_t)m * 512 + j0);
  bf16x8 a1 = *(const bf16x8*)(part + (size_t)(8192 + m) * 512 + j0);
  bf16x8 a2 = *(const bf16x8*)(part + (size_t)(16384 + m) * 512 + j0);
  bf16x8 a3 = *(const bf16x8*)(part + (size_t)(24576 + m) * 512 + j0);
  float s[8];
  #pragma unroll
  for (int i = 0; i < 8; ++i)
    s[i] = (bf2f((ushort)a0[i]) + bf2f((ushort)a1[i])) +
           (bf2f((ushort)a2[i]) + bf2f((ushort)a3[i]));
  int btg = m >> 4, f = m & 15;
  #pragma unroll
  for (int jj = 0; jj < 8; ++jj) {
    int j = j0 + jj;
    if (j < GJ) {
      int l = (j >= 1) + (j >= 10) + (j >= 35) + (j >= 84) + (j >= 165) + (j >= 286);
      int o    = sel7(l, 0, 1, 10, 35, 84, 165, 286);
      int d    = sel7(l, 1, 3, 5, 7, 9, 11, 13);
      int Kp   = sel7(l, 64, 64, 128, 128, 192, 192, 256);
      int Aoff = sel7(l, 0, 32768, 131072, 458752, 917504, 1802240, 2883584);
      float rcpd = sel7f(l, 1.f, 1.f / 3.f, 0.2f, 1.f / 7.f, 1.f / 9.f,
                         1.f / 11.f, 1.f / 13.f);
      int jl = j - o;
      int u = (int)(((float)jl + 0.5f) * rcpd);
      int mB = jl - u * d;
      Abuf[(size_t)Aoff + ((size_t)btg * d + mB) * Kp + f * d + u] = f2bf(s[jj]);
    }
  }
}

// ---------------- k_mm2f: fallback combined GEMM (unchanged) ----------------
__global__ __launch_bounds__(256) void k_mm2f(const ushort* __restrict__ A,
                                              const ushort* __restrict__ Bm,
                                              ushort* __restrict__ Abuf) {
  __shared__ __align__(16) short Asb[2][128 * 64];
  __shared__ __align__(16) short Bsb[2][128 * 64];
  int tid = threadIdx.x;
  int lane = tid & 63, wid = tid >> 6;
  int quad = lane >> 4, lr = lane & 15;
  int wm = wid >> 1, wn = wid & 1;
  int bid = blockIdx.x;
  int mb = bid & 63, nb = bid >> 6;
  f32x4 acc[4][4];
  #pragma unroll
  for (int a = 0; a < 4; ++a)
    #pragma unroll
    for (int b = 0; b < 4; ++b) acc[a][b] = (f32x4){0.f, 0.f, 0.f, 0.f};
  const ushort* Ab = A + (size_t)mb * 128 * GG;
  const ushort* Bb = Bm + (size_t)nb * 128 * GG;
  auto stage = [&](int buf, int kc) {
    #pragma unroll
    for (int it = 0; it < 4; ++it) {
      int s0 = (wid * 4 + it) * 64;
      int s = s0 + lane;
      int r = s >> 3, pp = s & 7, p = pp ^ (r & 7);
      __builtin_amdgcn_global_load_lds(
          (const __attribute__((address_space(1))) u32*)(Ab + (size_t)r * GG + kc + p * 8),
          (__attribute__((address_space(3))) u32*)(&Asb[buf][s0 * 8]), 16, 0, 0);
    }
    #pragma unroll
    for (int it = 0; it < 4; ++it) {
      int s0 = (wid * 4 + it) * 64;
      int s = s0 + lane;
      int r = s >> 3, pp = s & 7, p = pp ^ (r & 7);
      __builtin_amdgcn_global_load_lds(
          (const __attribute__((address_space(1))) u32*)(Bb + (size_t)r * GG + kc + p * 8),
          (__attribute__((address_space(3))) u32*)(&Bsb[buf][s0 * 8]), 16, 0, 0);
    }
  };
  stage(0, 0);
  __syncthreads();
  for (int it = 0; it < 64; ++it) {
    int cur = it & 1;
    if (it < 63) stage(cur ^ 1, (it + 1) * 64);
    #pragma unroll
    for (int ks = 0; ks < 2; ++ks) {
      bf16x8 af[4], bvv[4];
      #pragma unroll
      for (int mt = 0; mt < 4; ++mt) {
        int ra = wm * 64 + mt * 16 + lr;
        int v = (ks * 4 + quad) ^ (ra & 7);
        af[mt] = *(const bf16x8*)&Asb[cur][(ra * 8 + v) * 8];
      }
      #pragma unroll
      for (int nt = 0; nt < 4; ++nt) {
        int rb = wn * 64 + nt * 16 + lr;
        int v = (ks * 4 + quad) ^ (rb & 7);
        bvv[nt] = *(const bf16x8*)&Bsb[cur][(rb * 8 + v) * 8];
      }
      #pragma unroll
      for (int mt = 0; mt < 4; ++mt)
        #pragma unroll
        for (int nt = 0; nt < 4; ++nt)
          acc[mt][nt] = __builtin_amdgcn_mfma_f32_16x16x32_bf16(af[mt], bvv[nt], acc[mt][nt], 0, 0, 0);
    }
    __syncthreads();
  }
  #pragma unroll
  for (int nt = 0; nt < 4; ++nt) {
    int j = nb * 128 + wn * 64 + nt * 16 + lr;
    if (j < GJ) {
      int l = (j >= 1) + (j >= 10) + (j >= 35) + (j >= 84) + (j >= 165) + (j >= 286);
      int o    = sel7(l, 0, 1, 10, 35, 84, 165, 286);
      int d    = sel7(l, 1, 3, 5, 7, 9, 11, 13);
      int Kp   = sel7(l, 64, 64, 128, 128, 192, 192, 256);
      int Aoff = sel7(l, 0, 32768, 131072, 458752, 917504, 1802240, 2883584);
      int jl = j - o;
      float rcpd = 1.0f / (float)d;
      int u = (int)(((float)jl + 0.5f) * rcpd);
      int mB = jl - u * d;
      #pragma unroll
      for (int mt = 0; mt < 4; ++mt)
        #pragma unroll
        for (int r = 0; r < 4; ++r) {
          int m = mb * 128 + wm * 64 + mt * 16 + quad * 4 + r;
          int btg = m >> 4, f = m & 15;
          Abuf[(size_t)Aoff + ((size_t)btg * d + mB) * Kp + f * d + u] =
              f2bf(acc[mt][nt][r]);
        }
    }
  }
}

// ---------------- k_batchX: per-l GEMMs (+ xg in fallback), single-buffer ----------------
__global__ __launch_bounds__(256) void k_batchX(const ushort* __restrict__ Abuf,
                                                const ushort* __restrict__ Bbuf,
                                                const float* __restrict__ x,
                                                const ushort* __restrict__ icoBx,
                                                ushort* __restrict__ trajbf,
                                                float* __restrict__ xg) {
  __shared__ __align__(16) short As[128 * 64];   // 16 KB
  __shared__ __align__(16) short Bs[128 * 64];   // 16 KB
  int bid = blockIdx.x;
  int tid = threadIdx.x;
  int lane = tid & 63, wid = tid >> 6;
  int quad = lane >> 4, lr = lane & 15;
  int wm = wid >> 1, wn = wid & 1;

  if (bid >= 1008) {
    // ---- xg path (fallback only; main path grid stops at 1008).
    int mtile = bid - 1008;                          // 0..127
    f32x4 acc[4][2];
    #pragma unroll
    for (int a = 0; a < 4; ++a)
      #pragma unroll
      for (int b = 0; b < 2; ++b) acc[a][b] = (f32x4){0.f, 0.f, 0.f, 0.f};
    float xn[32];
    auto loadx = [&](int itk) {
      #pragma unroll
      for (int g = 0; g < 4; ++g) {
        int s = g * 256 + tid;
        int r = s >> 3, p8 = s & 7, p = p8 ^ (r & 7);
        const float* xr = x + (size_t)(mtile * 128 + r) * GJ;
        int j0 = itk * 64 + p * 8;
        #pragma unroll
        for (int jj = 0; jj < 8; ++jj) {
          int j = j0 + jj;
          xn[g * 8 + jj] = (j < GJ) ? xr[j] : 0.f;
        }
      }
    };
    auto writex = [&]() {
      #pragma unroll
      for (int g = 0; g < 4; ++g) {
        int s = g * 256 + tid;
        bf16x8 v8;
        #pragma unroll
        for (int jj = 0; jj < 8; ++jj) v8[jj] = (short)f2bf(xn[g * 8 + jj]);
        *(bf16x8*)&As[s * 8] = v8;
      }
    };
    auto stageBx = [&](int kc) {
      #pragma unroll
      for (int it = 0; it < 2; ++it) {
        int s0 = (wid * 2 + it) * 64;
        int s = s0 + lane;
        int r = s >> 3, p8 = s & 7, p = p8 ^ (r & 7);
        const ushort* gb = icoBx + (size_t)r * JP + kc + p * 8;
        __builtin_amdgcn_global_load_lds(
            (const __attribute__((address_space(1))) u32*)gb,
            (__attribute__((address_space(3))) u32*)(Bs + s0 * 8), 16, 0, 0);
      }
    };
    loadx(0); writex(); stageBx(0);
    __syncthreads();
    for (int it = 0; it < 8; ++it) {
      if (it < 7) loadx(it + 1);
      #pragma unroll
      for (int ks = 0; ks < 2; ++ks) {
        bf16x8 af[4], bv[2];
        #pragma unroll
        for (int mt = 0; mt < 4; ++mt) {
          int ra = wm * 64 + mt * 16 + lr;
          int v = (ks * 4 + quad) ^ (ra & 7);
          af[mt] = *(const bf16x8*)&As[(ra * 8 + v) * 8];
        }
        #pragma unroll
        for (int nt = 0; nt < 2; ++nt) {
          int rb = wn * 32 + nt * 16 + lr;
          int v = (ks * 4 + quad) ^ (rb & 7);
          bv[nt] = *(const bf16x8*)&Bs[(rb * 8 + v) * 8];
        }
        #pragma unroll
        for (int mt = 0; mt < 4; ++mt)
          #pragma unroll
          for (int nt = 0; nt < 2; ++nt)
            acc[mt][nt] = __builtin_amdgcn_mfma_f32_16x16x32_bf16(af[mt], bv[nt], acc[mt][nt], 0, 0, 0);
      }
      if (it < 7) {
        __syncthreads();
        writex();
        stageBx((it + 1) * 64);
        __syncthreads();
      }
    }
    #pragma unroll
    for (int mt = 0; mt < 4; ++mt)
      #pragma unroll
      for (int nt = 0; nt < 2; ++nt) {
        int i = wn * 32 + nt * 16 + lr;
        if (i < NICO) {
          #pragma unroll
          for (int r = 0; r < 4; ++r) {
            int row = mtile * 128 + wm * 64 + mt * 16 + quad * 4 + r;
            xg[(size_t)row * NICO + i] = acc[mt][nt][r];
          }
        }
      }
    return;
  }

  // ---- per-l path: 128x128 tile, single-buffer.
  f32x4 acc[4][4];
  #pragma unroll
  for (int a = 0; a < 4; ++a)
    #pragma unroll
    for (int b = 0; b < 4; ++b) acc[a][b] = (f32x4){0.f, 0.f, 0.f, 0.f};

  int l = (bid >= 4) + (bid >= 28) + (bid >= 88) + (bid >= 200) +
          (bid >= 380) + (bid >= 644);
  int bbase = sel7(l, 0, 4, 28, 88, 200, 380, 644);
  int d     = sel7(l, 1, 3, 5, 7, 9, 11, 13);
  int Kp    = sel7(l, 64, 64, 128, 128, 192, 192, 256);
  int o     = sel7(l, 0, 1, 10, 35, 84, 165, 286);
  int Aoff  = sel7(l, 0, 32768, 131072, 458752, 917504, 1802240, 2883584);
  int Boff  = sel7(l, 0, 4096, 16384, 57344, 114688, 225280, 360448);
  int ntc   = sel7(l, 1, 2, 3, 4, 5, 6, 7);         // ceil(64d/128)
  float rcpntc = sel7f(l, 1.f, 0.5f, 1.f / 3.f, 0.25f, 0.2f, 1.f / 6.f, 1.f / 7.f);
  float rcpd   = sel7f(l, 1.f, 1.f / 3.f, 0.2f, 1.f / 7.f, 1.f / 9.f,
                       1.f / 11.f, 1.f / 13.f);
  int t = bid - bbase;
  int mtile = (int)(((float)t + 0.5f) * rcpntc);    // exact (margin >> eps)
  int ntile = t - mtile * ntc;
  int Nl = 64 * d;

  const ushort* Ab = Abuf + Aoff + (size_t)mtile * 128 * Kp;
  const ushort* Bb = Bbuf + Boff + (size_t)ntile * 128 * Kp;

  auto stage = [&](int kc) {
    #pragma unroll
    for (int it = 0; it < 4; ++it) {
      int s0 = (wid * 4 + it) * 64;
      int s = s0 + lane;
      int r = s >> 3, pp = s & 7, p = pp ^ (r & 7);
      __builtin_amdgcn_global_load_lds(
          (const __attribute__((address_space(1))) u32*)(Ab + (size_t)r * Kp + kc + p * 8),
          (__attribute__((address_space(3))) u32*)(As + s0 * 8), 16, 0, 0);
    }
    #pragma unroll
    for (int it = 0; it < 4; ++it) {
      int s0 = (wid * 4 + it) * 64;
      int s = s0 + lane;
      int r = s >> 3, pp = s & 7, p = pp ^ (r & 7);
      __builtin_amdgcn_global_load_lds(
          (const __attribute__((address_space(1))) u32*)(Bb + (size_t)r * Kp + kc + p * 8),
          (__attribute__((address_space(3))) u32*)(Bs + s0 * 8), 16, 0, 0);
    }
  };

  int nIter = Kp >> 6;                               // 1..4
  for (int it = 0; it < nIter; ++it) {
    if (it) __syncthreads();                         // WAR on LDS
    stage(it * 64);
    __syncthreads();                                 // drains vmcnt
    #pragma unroll
    for (int ks = 0; ks < 2; ++ks) {
      bf16x8 af[4], bv[4];
      #pragma unroll
      for (int mt = 0; mt < 4; ++mt) {
        int ra = wm * 64 + mt * 16 + lr;
        int v = (ks * 4 + quad) ^ (ra & 7);
        af[mt] = *(const bf16x8*)&As[(ra * 8 + v) * 8];
      }
      #pragma unroll
      for (int nt = 0; nt < 4; ++nt) {
        int rb = wn * 64 + nt * 16 + lr;
        int v = (ks * 4 + quad) ^ (rb & 7);
        bv[nt] = *(const bf16x8*)&Bs[(rb * 8 + v) * 8];
      }
      #pragma unroll
      for (int mt = 0; mt < 4; ++mt)
        #pragma unroll
        for (int nt = 0; nt < 4; ++nt)
          acc[mt][nt] = __builtin_amdgcn_mfma_f32_16x16x32_bf16(af[mt], bv[nt], acc[mt][nt], 0, 0, 0);
    }
  }
  // kappa-permuted scatter: index o + m*d + v (consecutive v -> contiguous)
  #pragma unroll
  for (int nt = 0; nt < 4; ++nt) {
    int Ncol = ntile * 128 + wn * 64 + nt * 16 + lr;
    if (Ncol < Nl) {
      int g2 = (int)(((float)Ncol + 0.5f) * rcpd);
      int v = Ncol - g2 * d;
      #pragma unroll
      for (int mt = 0; mt < 4; ++mt)
        #pragma unroll
        for (int r = 0; r < 4; ++r) {
          int Mrow = mtile * 128 + wm * 64 + mt * 16 + quad * 4 + r;
          int bt = (int)(((float)Mrow + 0.5f) * rcpd);
          int m = Mrow - bt * d;
          trajbf[(size_t)(bt * 64 + g2) * JP + o + m * d + v] = f2bf(acc[mt][nt][r]);
        }
    }
  }
}

// ---------------- k_icoT: trajo = trajbf . icoB^T, single-buffer (unchanged) ----------------
__global__ __launch_bounds__(256) void k_icoT(const ushort* __restrict__ trajbf,
                                              const ushort* __restrict__ icoB,
                                              float* __restrict__ trajo) {
  __shared__ __align__(16) short As[128 * 64];   // 16 KB
  __shared__ __align__(16) short Bs[64 * 64];    // 8 KB
  int mtile = blockIdx.x;                         // 0..255
  int tid = threadIdx.x;
  int lane = tid & 63, wid = tid >> 6;
  int quad = lane >> 4, lr = lane & 15;
  int wm = wid >> 1, wn = wid & 1;
  f32x4 acc[4][2];
  #pragma unroll
  for (int a = 0; a < 4; ++a)
    #pragma unroll
    for (int b = 0; b < 2; ++b) acc[a][b] = (f32x4){0.f, 0.f, 0.f, 0.f};

  auto stage = [&](int kc) {
    #pragma unroll
    for (int it = 0; it < 4; ++it) {
      int s0 = (wid * 4 + it) * 64;
      int s = s0 + lane;
      int r = s >> 3, p8 = s & 7, p = p8 ^ (r & 7);
      const ushort* ga = trajbf + (size_t)(mtile * 128 + r) * JP + kc + p * 8;
      __builtin_amdgcn_global_load_lds(
          (const __attribute__((address_space(1))) u32*)ga,
          (__attribute__((address_space(3))) u32*)(As + s0 * 8), 16, 0, 0);
    }
    #pragma unroll
    for (int it = 0; it < 2; ++it) {
      int s0 = (wid * 2 + it) * 64;
      int s = s0 + lane;
      int r = s >> 3, p8 = s & 7, p = p8 ^ (r & 7);
      const ushort* gb = icoB + (size_t)r * JP + kc + p * 8;
      __builtin_amdgcn_global_load_lds(
          (const __attribute__((address_space(1))) u32*)gb,
          (__attribute__((address_space(3))) u32*)(Bs + s0 * 8), 16, 0, 0);
    }
  };

  for (int it = 0; it < 8; ++it) {
    if (it) __syncthreads();                         // WAR on LDS
    stage(it * 64);
    __syncthreads();                                 // drains vmcnt
    #pragma unroll
    for (int ks = 0; ks < 2; ++ks) {
      bf16x8 af[4], bv[2];
      #pragma unroll
      for (int mt = 0; mt < 4; ++mt) {
        int ra = wm * 64 + mt * 16 + lr;
        int v = (ks * 4 + quad) ^ (ra & 7);
        af[mt] = *(const bf16x8*)&As[(ra * 8 + v) * 8];
      }
      #pragma unroll
      for (int nt = 0; nt < 2; ++nt) {
        int rb = wn * 32 + nt * 16 + lr;
        int v = (ks * 4 + quad) ^ (rb & 7);
        bv[nt] = *(const bf16x8*)&Bs[(rb * 8 + v) * 8];
      }
      #pragma unroll
      for (int mt = 0; mt < 4; ++mt)
        #pragma unroll
        for (int nt = 0; nt < 2; ++nt)
          acc[mt][nt] = __builtin_amdgcn_mfma_f32_16x16x32_bf16(af[mt], bv[nt], acc[mt][nt], 0, 0, 0);
    }
  }
  #pragma unroll
  for (int mt = 0; mt < 4; ++mt)
    #pragma unroll
    for (int nt = 0; nt < 2; ++nt) {
      int i = wn * 32 + nt * 16 + lr;
      if (i < NICO) {
        #pragma unroll
        for (int r = 0; r < 4; ++r) {
          int row = mtile * 128 + wm * 64 + mt * 16 + quad * 4 + r;
          trajo[(size_t)row * NICO + i] = acc[mt][nt][r];
        }
      }
    }
}

extern "C" void kernel_launch(void* const* d_in, const int* in_sizes, int n_in,
                              void* d_out, int out_size, void* d_ws, size_t ws_size,
                              hipStream_t stream) {
  const float *x = nullptr, *traj = nullptr, *w1s = nullptr, *w1v = nullptr;
  const float *Din = nullptr, *Dout = nullptr, *ico = nullptr;
  W7 w2{};
  for (int i = 0; i < n_in; ++i) {
    const float* p = (const float*)d_in[i];
    switch (in_sizes[i]) {
      case 7454720: x = p; break;
      case 5120:    traj = p; break;
      case 16:      w1s = p; break;
      case 144:     w1v = p; break;
      case 40960:   Din = p; break;
      case 1863680: Dout = p; break;
      case 27300:   ico = p; break;
      case 1024:    w2.p[0] = p; break;
      case 9216:    w2.p[1] = p; break;
      case 25600:   w2.p[2] = p; break;
      case 50176:   w2.p[3] = p; break;
      case 82944:   w2.p[4] = p; break;
      case 123904:  w2.p[5] = p; break;
      case 173056:  w2.p[6] = p; break;
      default: break;
    }
  }
  // ws layout (bytes):
  //   h       @ 0            (327,680)
  //   DoutBT  @ 327,680      (4,194,304)
  //   icoB    @ 4,521,984    (65,536)   [kappa-permuted]
  //   icoBx   @ 4,587,520    (65,536)   [j-order, for xg]
  //   Abuf    @ 4,653,056    (9,175,040)
  //   Bbuf    @ 13,828,096   (1,146,880)
  //   sigb    @ 14,974,976   (67,108,864)
  //     trajbf aliases sigb[0, 33.5MB)
  //     part (4 splits, 33.5MB) aliases sigb[33.5MB, 67MB)
  //   DinB    @ 82,083,840   (262,144)  [main path only]
  char* wsb = (char*)d_ws;
  float*  h       = (float*)wsb;
  ushort* DoutBT  = (ushort*)(wsb + 327680);
  ushort* icoB    = (ushort*)(wsb + 4521984);
  ushort* icoBx   = (ushort*)(wsb + 4587520);
  ushort* Abuf    = (ushort*)(wsb + 4653056);
  ushort* Bbuf    = (ushort*)(wsb + 13828096);
  ushort* sigb    = (ushort*)(wsb + 14974976);
  ushort* trajbf  = sigb;
  ushort* part    = (ushort*)(wsb + 48529408);
  ushort* DinB    = (ushort*)(wsb + 82083840);
  float* xg    = (float*)d_out;
  float* trajo = (float*)d_out + 983040;

  bool mainpath = ws_size >= 115638272ULL;

  k_pre<<<dim3(5584), dim3(256), 0, stream>>>(traj, w1s, w1v, ico, Dout, Din,
                                              w2, h, icoB, icoBx, DoutBT, Abuf,
                                              Bbuf, mainpath ? DinB : nullptr);
  if (mainpath) {
    // xg GEMM (independent of the sig chain) co-runs inside k_fsig's grid.
    k_fsig<<<dim3(1152), dim3(256), 0, stream>>>(h, DinB, DoutBT, part,
                                                 x, icoBx, xg);
    k_red <<<dim3(2048), dim3(256), 0, stream>>>(part, Abuf);
    k_batchX<<<dim3(1008), dim3(256), 0, stream>>>(Abuf, Bbuf, x, icoBx,
                                                   trajbf, xg);
  } else {
    k_sig<<<dim3(2, 512), dim3(256), 0, stream>>>(h, Din, sigb);
    k_mm2f<<<dim3(256),  dim3(256), 0, stream>>>(sigb, DoutBT, Abuf);
    k_batchX<<<dim3(1136), dim3(256), 0, stream>>>(Abuf, Bbuf, x, icoBx,
                                                   trajbf, xg);
  }
  k_icoT<<<dim3(256), dim3(256), 0, stream>>>(trajbf, icoB, trajo);
}